// Round 2
// baseline (1120.274 us; speedup 1.0000x reference)
//
#include <hip/hip_runtime.h>
#include <stdint.h>

#define M_DIM 2048
#define K_DIM 8192
#define N_Q   8192
#define N_KV  1024
#define N_TOT (N_Q + 2 * N_KV)   // 10240
#define BM    128
#define BN    128
#define BK    32
#define NIT   (K_DIM / BK)       // 256 K-iterations

typedef __bf16 bf16x8 __attribute__((ext_vector_type(8)));
typedef __bf16 bf16x2 __attribute__((ext_vector_type(2)));
typedef float  f32x4  __attribute__((ext_vector_type(4)));

// ---------------------------------------------------------------------------
// Pass 1a: cast x f32 -> bf16 (row-major [M][K] unchanged)
// ---------------------------------------------------------------------------
__global__ __launch_bounds__(256) void xcast(const float* __restrict__ x,
                                             __bf16* __restrict__ xb) {
    size_t i = ((size_t)blockIdx.x * 256 + threadIdx.x) * 8;
    f32x4 a = *(const f32x4*)(x + i);
    f32x4 b = *(const f32x4*)(x + i + 4);
    bf16x8 o = { (__bf16)a.x, (__bf16)a.y, (__bf16)a.z, (__bf16)a.w,
                 (__bf16)b.x, (__bf16)b.y, (__bf16)b.z, (__bf16)b.w };
    *(bf16x8*)(xb + i) = o;
}

// ---------------------------------------------------------------------------
// Pass 1b: cast + transpose W (f32 [K][N] -> bf16 [N][K]), q|k|v concatenated
// along N. FIX vs last round: destination row base (cdst) is the CONCATENATED
// N index (+N_Q for wk, +N_Q+N_KV for wv); csrc stays local to the source W.
// 64x64 tiles via LDS; stride 65 dwords -> conflict-light on both sides.
// ---------------------------------------------------------------------------
__global__ __launch_bounds__(256) void wcast_t(const float* __restrict__ wq,
                                               const float* __restrict__ wk,
                                               const float* __restrict__ wv,
                                               __bf16* __restrict__ wt) {
    __shared__ float sT[64 * 65];
    const uint32_t bid   = blockIdx.x;
    const uint32_t ktile = bid & 127;   // 8192/64 = 128 k-tiles (fast-moving)
    const uint32_t ntile = bid >> 7;    // 160 n-tiles
    const float* W; uint32_t ldW, csrc, cdst;
    if (ntile < 128)      { W = wq; ldW = N_Q;  csrc = ntile * 64;
                            cdst = csrc; }
    else if (ntile < 144) { W = wk; ldW = N_KV; csrc = (ntile - 128) * 64;
                            cdst = N_Q + csrc; }
    else                  { W = wv; ldW = N_KV; csrc = (ntile - 144) * 64;
                            cdst = N_Q + N_KV + csrc; }
    const uint32_t k0 = ktile * 64;
    const uint32_t t  = threadIdx.x;

    // load 64 rows x 64 cols f32, coalesced (16 lanes x 16B = 256B per row)
    const uint32_t lr = t >> 4;
    const uint32_t lc = (t & 15) * 4;
    const float* gp = W + (size_t)(k0 + lr) * ldW + csrc + lc;
    #pragma unroll
    for (int i = 0; i < 4; ++i) {
        f32x4 v = *(const f32x4*)(gp + (size_t)i * 16 * ldW);
        float* d = &sT[(lr + i * 16) * 65 + lc];
        d[0] = v.x; d[1] = v.y; d[2] = v.z; d[3] = v.w;
    }
    __syncthreads();

    // write 64 n-rows of WT, 64 k each; 8 lanes x bf16x8 = 128B per n-row
    const uint32_t wn  = t >> 3;       // 0..31 (+32 on 2nd pass)
    const uint32_t wk8 = (t & 7) * 8;  // k offset
    #pragma unroll
    for (int it = 0; it < 2; ++it) {
        uint32_t n = wn + it * 32;
        bf16x8 o;
        #pragma unroll
        for (int j = 0; j < 8; ++j) o[j] = (__bf16)sT[(wk8 + j) * 65 + n];
        *(bf16x8*)(wt + (size_t)(cdst + n) * K_DIM + k0 + wk8) = o;
    }
}

// ---------------------------------------------------------------------------
// Pass 2: bf16 B^T GEMM, m97 structure (128x128 tile, BK=32, 4 waves 2x2,
// global_load_lds dwordx4 staging, single LDS buffer, 2 barriers/K-step).
// Swizzle (rule #21): LDS dest linear, global SOURCE chunk pre-XOR'd by
// swz(r)=(r>>1)&3, frag ds_read applies the same XOR -> 2-way banks (free).
// ---------------------------------------------------------------------------
__device__ __forceinline__ void gload16(const void* g, void* l) {
    __builtin_amdgcn_global_load_lds(
        (const __attribute__((address_space(1))) void*)g,
        (__attribute__((address_space(3))) void*)l, 16, 0, 0);
}

__global__ __launch_bounds__(256) void qkv_mm(const __bf16* __restrict__ xb,
                                              const __bf16* __restrict__ wt,
                                              float* __restrict__ out) {
    __shared__ __align__(16) __bf16 sA[BM * BK];   // [m][k], chunk-swizzled data
    __shared__ __align__(16) __bf16 sB[BN * BK];   // [n][k], chunk-swizzled data

    const uint32_t tid = threadIdx.x;

    // XCD-bijective swizzle (1280 % 8 == 0): each XCD owns 10 consecutive
    // n-tiles (all 16 m-tiles) -> W slab reuse stays inside one L2.
    const uint32_t logical = (blockIdx.x & 7) * 160 + (blockIdx.x >> 3);
    const uint32_t mt = logical & 15;   // 16 m-tiles contiguous per n-tile
    const uint32_t nt = logical >> 4;   // 80 n-tiles
    const uint32_t m0 = mt * BM;
    const uint32_t n0 = nt * BN;

    // ---- staging maps: chunk c = w*128 + i*64 + lane; row = c>>2; LDS chunk
    // position (c&3) receives global chunk (c&3)^swz(row). LDS dest linear.
    const uint32_t w    = tid >> 6;
    const uint32_t lane = tid & 63;
    const __bf16* gA[2];
    const __bf16* gB[2];
    #pragma unroll
    for (int i = 0; i < 2; ++i) {
        uint32_t c  = w * 128 + i * 64 + lane;
        uint32_t r  = c >> 2;
        uint32_t qs = (c & 3) ^ ((r >> 1) & 3);
        gA[i] = xb + (size_t)(m0 + r) * K_DIM + qs * 8;
        gB[i] = wt + (size_t)(n0 + r) * K_DIM + qs * 8;
    }
    char* la = (char*)sA + w * 2048;   // wave-uniform LDS bases
    char* lb = (char*)sB + w * 2048;

    // ---- wave / lane decomposition (2x2 waves, each 64x64) ----
    const uint32_t wm   = (w >> 1) * 64;
    const uint32_t wn   = (w & 1) * 64;
    const uint32_t l15  = lane & 15;
    const uint32_t quad = lane >> 4;

    // frag read offsets (bf16 units): row*32 + (quad ^ swz(row))*8
    uint32_t a_off[4], b_off[4];
    #pragma unroll
    for (int t = 0; t < 4; ++t) {
        uint32_t ar = wm + t * 16 + l15;
        a_off[t] = ar * BK + ((quad ^ ((ar >> 1) & 3)) * 8);
        uint32_t br = wn + t * 16 + l15;
        b_off[t] = br * BK + ((quad ^ ((br >> 1) & 3)) * 8);
    }

    f32x4 acc[4][4] = {};

    for (uint32_t kt = 0; kt < NIT; ++kt) {
        // stage tile kt (async global->LDS, no VGPR round-trip, no VALU)
        gload16(gA[0], la);        gload16(gA[1], la + 1024);
        gload16(gB[0], lb);        gload16(gB[1], lb + 1024);
        gA[0] += BK; gA[1] += BK; gB[0] += BK; gB[1] += BK;

        __syncthreads();   // compiler drains vmcnt+lgkmcnt before s_barrier

        bf16x8 af[4], bf[4];
        #pragma unroll
        for (int t = 0; t < 4; ++t) {
            af[t] = *(const bf16x8*)(sA + a_off[t]);
            bf[t] = *(const bf16x8*)(sB + b_off[t]);
        }
        #pragma unroll
        for (int mi = 0; mi < 4; ++mi)
            #pragma unroll
            for (int ni = 0; ni < 4; ++ni)
                acc[mi][ni] = __builtin_amdgcn_mfma_f32_16x16x32_bf16(
                    af[mi], bf[ni], acc[mi][ni], 0, 0, 0);

        __syncthreads();   // frag reads done -> LDS reusable next iter
    }

    // ---- epilogue: head nt slab is contiguous [2048][128] f32 ----
    // C/D layout: col = lane&15, row = quad*4 + reg (m89/m91 verified)
    float* op = out + (size_t)nt * (M_DIM * 128) + (size_t)m0 * 128;
    #pragma unroll
    for (int mi = 0; mi < 4; ++mi) {
        #pragma unroll
        for (int r = 0; r < 4; ++r) {
            uint32_t row = wm + mi * 16 + quad * 4 + r;
            #pragma unroll
            for (int ni = 0; ni < 4; ++ni) {
                uint32_t col = wn + ni * 16 + l15;
                op[(size_t)row * 128 + col] = acc[mi][ni][r];
            }
        }
    }
}

// ---------------------------------------------------------------------------
// Fallback (round-0 verified kernel): used only if ws_size is too small.
// ---------------------------------------------------------------------------
__device__ __forceinline__ uint32_t swz_fb(uint32_t r) { return ((r >> 1) ^ (r >> 3)) & 3u; }

__device__ __forceinline__ uint32_t pack_bf16(float lo, float hi) {
    bf16x2 v = { (__bf16)lo, (__bf16)hi };
    return __builtin_bit_cast(uint32_t, v);
}

__global__ __launch_bounds__(256) void qkv_gemm(
    const float* __restrict__ x,
    const float* __restrict__ wq,
    const float* __restrict__ wk,
    const float* __restrict__ wv,
    float* __restrict__ out)
{
    __shared__ __align__(16) uint16_t sA[BM * BK];
    __shared__ __align__(16) uint16_t sB[BN * BK];
    uint32_t* sAu = (uint32_t*)sA;
    uint32_t* sBu = (uint32_t*)sB;

    const uint32_t tid    = threadIdx.x;
    const uint32_t bid    = blockIdx.x;
    const uint32_t mt_blk = bid & 15;
    const uint32_t nt_blk = bid >> 4;
    const uint32_t m0     = mt_blk * BM;

    const size_t QSZ = (size_t)64 * M_DIM * 128;
    const size_t KSZ = (size_t)8  * M_DIM * 128;
    const float* Wsel;
    uint32_t ldW, col0;
    size_t obase;
    if (nt_blk < 64)      { Wsel = wq; ldW = N_Q;  col0 = nt_blk * 128;
                            obase = (size_t)nt_blk * M_DIM * 128; }
    else if (nt_blk < 72) { Wsel = wk; ldW = N_KV; col0 = (nt_blk - 64) * 128;
                            obase = QSZ + (size_t)(nt_blk - 64) * M_DIM * 128; }
    else                  { Wsel = wv; ldW = N_KV; col0 = (nt_blk - 72) * 128;
                            obase = QSZ + KSZ + (size_t)(nt_blk - 72) * M_DIM * 128; }

    const float* agp = x + (size_t)(m0 + (tid >> 3)) * K_DIM + (tid & 7) * 4;
    uint32_t a_wr[4];
    #pragma unroll
    for (int i = 0; i < 4; ++i) {
        uint32_t r = i * 32 + (tid >> 3);
        a_wr[i] = r * 16 + ((((tid >> 1) & 3) ^ swz_fb(r)) * 4) + (tid & 1) * 2;
    }

    const uint32_t bk  = (tid >> 4) * 2;
    const uint32_t bn0 = (tid & 15) * 8;
    const float* bgp = Wsel + (size_t)bk * ldW + col0 + bn0;
    const uint32_t bkc = bk >> 3;
    const uint32_t bkd = (bk & 7) >> 1;

    f32x4 apre[4], bpre[4];
    #pragma unroll
    for (int i = 0; i < 4; ++i) apre[i] = *(const f32x4*)(agp + (size_t)i * 32 * K_DIM);
    bpre[0] = *(const f32x4*)(bgp);
    bpre[1] = *(const f32x4*)(bgp + 4);
    bpre[2] = *(const f32x4*)(bgp + ldW);
    bpre[3] = *(const f32x4*)(bgp + ldW + 4);

    const uint32_t lane = tid & 63;
    const uint32_t wid  = tid >> 6;
    const uint32_t wm   = (wid >> 1) * 64;
    const uint32_t wn   = (wid & 1) * 64;
    const uint32_t l15  = lane & 15;
    const uint32_t quad = lane >> 4;

    f32x4 acc[4][4] = {};

    uint32_t a_off[4], b_off[4];
    #pragma unroll
    for (int t = 0; t < 4; ++t) {
        uint32_t ar = wm + t * 16 + l15;
        a_off[t] = ar * BK + ((quad ^ swz_fb(ar)) * 8);
        uint32_t br = wn + t * 16 + l15;
        b_off[t] = br * BK + ((quad ^ swz_fb(br)) * 8);
    }

    const float* agp_n = agp + BK;
    const float* bgp_n = bgp + (size_t)BK * ldW;

    for (uint32_t kt = 0; kt < NIT; ++kt) {
        __syncthreads();

        #pragma unroll
        for (int i = 0; i < 4; ++i) {
            uint2 wv2;
            wv2.x = pack_bf16(apre[i].x, apre[i].y);
            wv2.y = pack_bf16(apre[i].z, apre[i].w);
            *(uint2*)&sAu[a_wr[i]] = wv2;
        }
        {
            const float* pk0 = (const float*)&bpre[0];
            const float* pk1 = (const float*)&bpre[2];
            #pragma unroll
            for (int j = 0; j < 8; ++j) {
                uint32_t n = bn0 + j;
                sBu[n * 16 + ((bkc ^ swz_fb(n)) * 4) + bkd] = pack_bf16(pk0[j], pk1[j]);
            }
        }

        if (kt + 1 < NIT) {
            #pragma unroll
            for (int i = 0; i < 4; ++i) apre[i] = *(const f32x4*)(agp_n + (size_t)i * 32 * K_DIM);
            bpre[0] = *(const f32x4*)(bgp_n);
            bpre[1] = *(const f32x4*)(bgp_n + 4);
            bpre[2] = *(const f32x4*)(bgp_n + ldW);
            bpre[3] = *(const f32x4*)(bgp_n + ldW + 4);
            agp_n += BK;
            bgp_n += (size_t)BK * ldW;
        }

        __syncthreads();

        bf16x8 af[4], bf[4];
        #pragma unroll
        for (int t = 0; t < 4; ++t) {
            af[t] = *(const bf16x8*)(sA + a_off[t]);
            bf[t] = *(const bf16x8*)(sB + b_off[t]);
        }
        #pragma unroll
        for (int mi = 0; mi < 4; ++mi)
            #pragma unroll
            for (int ni = 0; ni < 4; ++ni)
                acc[mi][ni] = __builtin_amdgcn_mfma_f32_16x16x32_bf16(
                    af[mi], bf[ni], acc[mi][ni], 0, 0, 0);
    }

    float* op = out + obase + (size_t)m0 * 128;
    #pragma unroll
    for (int mi = 0; mi < 4; ++mi) {
        #pragma unroll
        for (int r = 0; r < 4; ++r) {
            uint32_t row = wm + mi * 16 + quad * 4 + r;
            #pragma unroll
            for (int ni = 0; ni < 4; ++ni) {
                uint32_t col = wn + ni * 16 + l15;
                op[(size_t)row * 128 + col] = acc[mi][ni][r];
            }
        }
    }
}

extern "C" void kernel_launch(void* const* d_in, const int* in_sizes, int n_in,
                              void* d_out, int out_size, void* d_ws, size_t ws_size,
                              hipStream_t stream) {
    const float* x  = (const float*)d_in[0];
    const float* wq = (const float*)d_in[1];
    const float* wk = (const float*)d_in[2];
    const float* wv = (const float*)d_in[3];

    const size_t XB_BYTES = (size_t)M_DIM * K_DIM * 2;          //  33.6 MB
    const size_t WT_BYTES = (size_t)N_TOT * K_DIM * 2;          // 167.8 MB

    if (ws_size >= XB_BYTES + WT_BYTES) {
        __bf16* xb = (__bf16*)d_ws;
        __bf16* wt = (__bf16*)((char*)d_ws + XB_BYTES);
        xcast<<<dim3((M_DIM * K_DIM) / (256 * 8)), dim3(256), 0, stream>>>(x, xb);
        wcast_t<<<dim3((K_DIM / 64) * (N_TOT / 64)), dim3(256), 0, stream>>>(wq, wk, wv, wt);
        qkv_mm<<<dim3((M_DIM / BM) * (N_TOT / BN)), dim3(256), 0, stream>>>(xb, wt, (float*)d_out);
    } else {
        qkv_gemm<<<dim3((M_DIM / BM) * (N_TOT / BN)), dim3(256), 0, stream>>>(
            x, wq, wk, wv, (float*)d_out);
    }
}

// Round 3
// 916.082 us; speedup vs baseline: 1.2229x; 1.2229x over previous
//
#include <hip/hip_runtime.h>
#include <stdint.h>

#define M_DIM 2048
#define K_DIM 8192
#define N_Q   8192
#define N_KV  1024
#define N_TOT (N_Q + 2 * N_KV)   // 10240
#define BM    128
#define BN    128
#define BK    32
#define NIT   (K_DIM / BK)       // 256 K-iterations

typedef __bf16 bf16x8 __attribute__((ext_vector_type(8)));
typedef __bf16 bf16x2 __attribute__((ext_vector_type(2)));
typedef float  f32x4  __attribute__((ext_vector_type(4)));

// ---------------------------------------------------------------------------
// Pass 1a: cast x f32 -> bf16 (row-major [M][K] unchanged)
// ---------------------------------------------------------------------------
__global__ __launch_bounds__(256) void xcast(const float* __restrict__ x,
                                             __bf16* __restrict__ xb) {
    size_t i = ((size_t)blockIdx.x * 256 + threadIdx.x) * 8;
    f32x4 a = *(const f32x4*)(x + i);
    f32x4 b = *(const f32x4*)(x + i + 4);
    bf16x8 o = { (__bf16)a.x, (__bf16)a.y, (__bf16)a.z, (__bf16)a.w,
                 (__bf16)b.x, (__bf16)b.y, (__bf16)b.z, (__bf16)b.w };
    *(bf16x8*)(xb + i) = o;
}

// ---------------------------------------------------------------------------
// Pass 1b: cast + transpose W (f32 [K][N] -> bf16 [N][K]), q|k|v concatenated
// along N (cdst = concatenated index; csrc local to source matrix).
// 64x64 tiles via LDS; stride 65 dwords -> conflict-light on both sides.
// (verified round 2 — unchanged)
// ---------------------------------------------------------------------------
__global__ __launch_bounds__(256) void wcast_t(const float* __restrict__ wq,
                                               const float* __restrict__ wk,
                                               const float* __restrict__ wv,
                                               __bf16* __restrict__ wt) {
    __shared__ float sT[64 * 65];
    const uint32_t bid   = blockIdx.x;
    const uint32_t ktile = bid & 127;   // 8192/64 = 128 k-tiles (fast-moving)
    const uint32_t ntile = bid >> 7;    // 160 n-tiles
    const float* W; uint32_t ldW, csrc, cdst;
    if (ntile < 128)      { W = wq; ldW = N_Q;  csrc = ntile * 64;
                            cdst = csrc; }
    else if (ntile < 144) { W = wk; ldW = N_KV; csrc = (ntile - 128) * 64;
                            cdst = N_Q + csrc; }
    else                  { W = wv; ldW = N_KV; csrc = (ntile - 144) * 64;
                            cdst = N_Q + N_KV + csrc; }
    const uint32_t k0 = ktile * 64;
    const uint32_t t  = threadIdx.x;

    // load 64 rows x 64 cols f32, coalesced (16 lanes x 16B = 256B per row)
    const uint32_t lr = t >> 4;
    const uint32_t lc = (t & 15) * 4;
    const float* gp = W + (size_t)(k0 + lr) * ldW + csrc + lc;
    #pragma unroll
    for (int i = 0; i < 4; ++i) {
        f32x4 v = *(const f32x4*)(gp + (size_t)i * 16 * ldW);
        float* d = &sT[(lr + i * 16) * 65 + lc];
        d[0] = v.x; d[1] = v.y; d[2] = v.z; d[3] = v.w;
    }
    __syncthreads();

    // write 64 n-rows of WT, 64 k each; 8 lanes x bf16x8 = 128B per n-row
    const uint32_t wn  = t >> 3;       // 0..31 (+32 on 2nd pass)
    const uint32_t wk8 = (t & 7) * 8;  // k offset
    #pragma unroll
    for (int it = 0; it < 2; ++it) {
        uint32_t n = wn + it * 32;
        bf16x8 o;
        #pragma unroll
        for (int j = 0; j < 8; ++j) o[j] = (__bf16)sT[(wk8 + j) * 65 + n];
        *(bf16x8*)(wt + (size_t)(cdst + n) * K_DIM + k0 + wk8) = o;
    }
}

// ---------------------------------------------------------------------------
// Pass 2: bf16 B^T GEMM, 128x128 tile, BK=32, 4 waves 2x2, global_load_lds
// staging. NEW vs round 2: minimum-2-phase double-buffered pipeline (T3
// recipe) — issue tile k+1's stage BEFORE computing tile k, single
// __syncthreads per iteration. The barrier's vmcnt(0) drain now waits on
// loads that had the whole ds_read+MFMA phase in flight -> latency hidden.
// Swizzle (rule #21, verified): LDS dest linear, global SOURCE chunk
// pre-XOR'd by swz(r)=(r>>1)&3, frag ds_read applies the same XOR.
// ---------------------------------------------------------------------------
__device__ __forceinline__ void gload16(const void* g, void* l) {
    __builtin_amdgcn_global_load_lds(
        (const __attribute__((address_space(1))) void*)g,
        (__attribute__((address_space(3))) void*)l, 16, 0, 0);
}

__global__ __launch_bounds__(256) void qkv_mm(const __bf16* __restrict__ xb,
                                              const __bf16* __restrict__ wt,
                                              float* __restrict__ out) {
    __shared__ __align__(16) __bf16 sA[2][BM * BK];   // [m][k], chunk-swizzled
    __shared__ __align__(16) __bf16 sB[2][BN * BK];   // [n][k], chunk-swizzled

    const uint32_t tid = threadIdx.x;

    // XCD-bijective swizzle (1280 % 8 == 0): each XCD owns 10 consecutive
    // n-tiles (all 16 m-tiles) -> W slab reuse stays inside one L2.
    const uint32_t logical = (blockIdx.x & 7) * 160 + (blockIdx.x >> 3);
    const uint32_t mt = logical & 15;   // 16 m-tiles contiguous per n-tile
    const uint32_t nt = logical >> 4;   // 80 n-tiles
    const uint32_t m0 = mt * BM;
    const uint32_t n0 = nt * BN;

    // ---- staging maps: chunk c = w*128 + i*64 + lane; row = c>>2; LDS chunk
    // position (c&3) receives global chunk (c&3)^swz(row). LDS dest linear.
    const uint32_t w    = tid >> 6;
    const uint32_t lane = tid & 63;
    const __bf16* gA[2];
    const __bf16* gB[2];
    #pragma unroll
    for (int i = 0; i < 2; ++i) {
        uint32_t c  = w * 128 + i * 64 + lane;
        uint32_t r  = c >> 2;
        uint32_t qs = (c & 3) ^ ((r >> 1) & 3);
        gA[i] = xb + (size_t)(m0 + r) * K_DIM + qs * 8;
        gB[i] = wt + (size_t)(n0 + r) * K_DIM + qs * 8;
    }
    // wave-uniform LDS staging bases, per buffer
    char* laA[2]; char* laB[2];
    #pragma unroll
    for (int b = 0; b < 2; ++b) {
        laA[b] = (char*)(&sA[b][0]) + w * 2048;
        laB[b] = (char*)(&sB[b][0]) + w * 2048;
    }

    // ---- wave / lane decomposition (2x2 waves, each 64x64) ----
    const uint32_t wm   = (w >> 1) * 64;
    const uint32_t wn   = (w & 1) * 64;
    const uint32_t l15  = lane & 15;
    const uint32_t quad = lane >> 4;

    // frag read offsets (bf16 units, within one buffer): row*32 + (quad^swz)*8
    uint32_t a_off[4], b_off[4];
    #pragma unroll
    for (int t = 0; t < 4; ++t) {
        uint32_t ar = wm + t * 16 + l15;
        a_off[t] = ar * BK + ((quad ^ ((ar >> 1) & 3)) * 8);
        uint32_t br = wn + t * 16 + l15;
        b_off[t] = br * BK + ((quad ^ ((br >> 1) & 3)) * 8);
    }

    f32x4 acc[4][4] = {};

    // ---- prologue: stage tile 0 into buffer 0 ----
    gload16(gA[0], laA[0]); gload16(gA[1], laA[0] + 1024);
    gload16(gB[0], laB[0]); gload16(gB[1], laB[0] + 1024);
    gA[0] += BK; gA[1] += BK; gB[0] += BK; gB[1] += BK;
    __syncthreads();

    uint32_t cur = 0;
    for (uint32_t kt = 0; kt < NIT; ++kt) {
        const uint32_t nxt = cur ^ 1;
        // issue next tile's stage FIRST (flies under this tile's compute)
        if (kt + 1 < NIT) {
            gload16(gA[0], laA[nxt]); gload16(gA[1], laA[nxt] + 1024);
            gload16(gB[0], laB[nxt]); gload16(gB[1], laB[nxt] + 1024);
            gA[0] += BK; gA[1] += BK; gB[0] += BK; gB[1] += BK;
        }

        const __bf16* pA = &sA[cur][0];
        const __bf16* pB = &sB[cur][0];
        bf16x8 af[4], bfr[4];
        #pragma unroll
        for (int t = 0; t < 4; ++t) {
            af[t]  = *(const bf16x8*)(pA + a_off[t]);
            bfr[t] = *(const bf16x8*)(pB + b_off[t]);
        }
        #pragma unroll
        for (int mi = 0; mi < 4; ++mi)
            #pragma unroll
            for (int ni = 0; ni < 4; ++ni)
                acc[mi][ni] = __builtin_amdgcn_mfma_f32_16x16x32_bf16(
                    af[mi], bfr[ni], acc[mi][ni], 0, 0, 0);

        // single barrier: drains staging (vmcnt) AND guards LDS reuse
        __syncthreads();
        cur = nxt;
    }

    // ---- epilogue: head nt slab is contiguous [2048][128] f32 ----
    // C/D layout: col = lane&15, row = quad*4 + reg (m89/m91 verified)
    float* op = out + (size_t)nt * (M_DIM * 128) + (size_t)m0 * 128;
    #pragma unroll
    for (int mi = 0; mi < 4; ++mi) {
        #pragma unroll
        for (int r = 0; r < 4; ++r) {
            uint32_t row = wm + mi * 16 + quad * 4 + r;
            #pragma unroll
            for (int ni = 0; ni < 4; ++ni) {
                uint32_t col = wn + ni * 16 + l15;
                op[(size_t)row * 128 + col] = acc[mi][ni][r];
            }
        }
    }
}

// ---------------------------------------------------------------------------
// Fallback (round-0 verified kernel): used only if ws_size is too small.
// ---------------------------------------------------------------------------
__device__ __forceinline__ uint32_t swz_fb(uint32_t r) { return ((r >> 1) ^ (r >> 3)) & 3u; }

__device__ __forceinline__ uint32_t pack_bf16(float lo, float hi) {
    bf16x2 v = { (__bf16)lo, (__bf16)hi };
    return __builtin_bit_cast(uint32_t, v);
}

__global__ __launch_bounds__(256) void qkv_gemm(
    const float* __restrict__ x,
    const float* __restrict__ wq,
    const float* __restrict__ wk,
    const float* __restrict__ wv,
    float* __restrict__ out)
{
    __shared__ __align__(16) uint16_t sA[BM * BK];
    __shared__ __align__(16) uint16_t sB[BN * BK];
    uint32_t* sAu = (uint32_t*)sA;
    uint32_t* sBu = (uint32_t*)sB;

    const uint32_t tid    = threadIdx.x;
    const uint32_t bid    = blockIdx.x;
    const uint32_t mt_blk = bid & 15;
    const uint32_t nt_blk = bid >> 4;
    const uint32_t m0     = mt_blk * BM;

    const size_t QSZ = (size_t)64 * M_DIM * 128;
    const size_t KSZ = (size_t)8  * M_DIM * 128;
    const float* Wsel;
    uint32_t ldW, col0;
    size_t obase;
    if (nt_blk < 64)      { Wsel = wq; ldW = N_Q;  col0 = nt_blk * 128;
                            obase = (size_t)nt_blk * M_DIM * 128; }
    else if (nt_blk < 72) { Wsel = wk; ldW = N_KV; col0 = (nt_blk - 64) * 128;
                            obase = QSZ + (size_t)(nt_blk - 64) * M_DIM * 128; }
    else                  { Wsel = wv; ldW = N_KV; col0 = (nt_blk - 72) * 128;
                            obase = QSZ + KSZ + (size_t)(nt_blk - 72) * M_DIM * 128; }

    const float* agp = x + (size_t)(m0 + (tid >> 3)) * K_DIM + (tid & 7) * 4;
    uint32_t a_wr[4];
    #pragma unroll
    for (int i = 0; i < 4; ++i) {
        uint32_t r = i * 32 + (tid >> 3);
        a_wr[i] = r * 16 + ((((tid >> 1) & 3) ^ swz_fb(r)) * 4) + (tid & 1) * 2;
    }

    const uint32_t bk  = (tid >> 4) * 2;
    const uint32_t bn0 = (tid & 15) * 8;
    const float* bgp = Wsel + (size_t)bk * ldW + col0 + bn0;
    const uint32_t bkc = bk >> 3;
    const uint32_t bkd = (bk & 7) >> 1;

    f32x4 apre[4], bpre[4];
    #pragma unroll
    for (int i = 0; i < 4; ++i) apre[i] = *(const f32x4*)(agp + (size_t)i * 32 * K_DIM);
    bpre[0] = *(const f32x4*)(bgp);
    bpre[1] = *(const f32x4*)(bgp + 4);
    bpre[2] = *(const f32x4*)(bgp + ldW);
    bpre[3] = *(const f32x4*)(bgp + ldW + 4);

    const uint32_t lane = tid & 63;
    const uint32_t wid  = tid >> 6;
    const uint32_t wm   = (wid >> 1) * 64;
    const uint32_t wn   = (wid & 1) * 64;
    const uint32_t l15  = lane & 15;
    const uint32_t quad = lane >> 4;

    f32x4 acc[4][4] = {};

    uint32_t a_off[4], b_off[4];
    #pragma unroll
    for (int t = 0; t < 4; ++t) {
        uint32_t ar = wm + t * 16 + l15;
        a_off[t] = ar * BK + ((quad ^ swz_fb(ar)) * 8);
        uint32_t br = wn + t * 16 + l15;
        b_off[t] = br * BK + ((quad ^ swz_fb(br)) * 8);
    }

    const float* agp_n = agp + BK;
    const float* bgp_n = bgp + (size_t)BK * ldW;

    for (uint32_t kt = 0; kt < NIT; ++kt) {
        __syncthreads();

        #pragma unroll
        for (int i = 0; i < 4; ++i) {
            uint2 wv2;
            wv2.x = pack_bf16(apre[i].x, apre[i].y);
            wv2.y = pack_bf16(apre[i].z, apre[i].w);
            *(uint2*)&sAu[a_wr[i]] = wv2;
        }
        {
            const float* pk0 = (const float*)&bpre[0];
            const float* pk1 = (const float*)&bpre[2];
            #pragma unroll
            for (int j = 0; j < 8; ++j) {
                uint32_t n = bn0 + j;
                sBu[n * 16 + ((bkc ^ swz_fb(n)) * 4) + bkd] = pack_bf16(pk0[j], pk1[j]);
            }
        }

        if (kt + 1 < NIT) {
            #pragma unroll
            for (int i = 0; i < 4; ++i) apre[i] = *(const f32x4*)(agp_n + (size_t)i * 32 * K_DIM);
            bpre[0] = *(const f32x4*)(bgp_n);
            bpre[1] = *(const f32x4*)(bgp_n + 4);
            bpre[2] = *(const f32x4*)(bgp_n + ldW);
            bpre[3] = *(const f32x4*)(bgp_n + ldW + 4);
            agp_n += BK;
            bgp_n += (size_t)BK * ldW;
        }

        __syncthreads();

        bf16x8 af[4], bf[4];
        #pragma unroll
        for (int t = 0; t < 4; ++t) {
            af[t] = *(const bf16x8*)(sA + a_off[t]);
            bf[t] = *(const bf16x8*)(sB + b_off[t]);
        }
        #pragma unroll
        for (int mi = 0; mi < 4; ++mi)
            #pragma unroll
            for (int ni = 0; ni < 4; ++ni)
                acc[mi][ni] = __builtin_amdgcn_mfma_f32_16x16x32_bf16(
                    af[mi], bf[ni], acc[mi][ni], 0, 0, 0);
    }

    float* op = out + obase + (size_t)m0 * 128;
    #pragma unroll
    for (int mi = 0; mi < 4; ++mi) {
        #pragma unroll
        for (int r = 0; r < 4; ++r) {
            uint32_t row = wm + mi * 16 + quad * 4 + r;
            #pragma unroll
            for (int ni = 0; ni < 4; ++ni) {
                uint32_t col = wn + ni * 16 + l15;
                op[(size_t)row * 128 + col] = acc[mi][ni][r];
            }
        }
    }
}

extern "C" void kernel_launch(void* const* d_in, const int* in_sizes, int n_in,
                              void* d_out, int out_size, void* d_ws, size_t ws_size,
                              hipStream_t stream) {
    const float* x  = (const float*)d_in[0];
    const float* wq = (const float*)d_in[1];
    const float* wk = (const float*)d_in[2];
    const float* wv = (const float*)d_in[3];

    const size_t XB_BYTES = (size_t)M_DIM * K_DIM * 2;          //  33.6 MB
    const size_t WT_BYTES = (size_t)N_TOT * K_DIM * 2;          // 167.8 MB

    if (ws_size >= XB_BYTES + WT_BYTES) {
        __bf16* xb = (__bf16*)d_ws;
        __bf16* wt = (__bf16*)((char*)d_ws + XB_BYTES);
        xcast<<<dim3((M_DIM * K_DIM) / (256 * 8)), dim3(256), 0, stream>>>(x, xb);
        wcast_t<<<dim3((K_DIM / 64) * (N_TOT / 64)), dim3(256), 0, stream>>>(wq, wk, wv, wt);
        qkv_mm<<<dim3((M_DIM / BM) * (N_TOT / BN)), dim3(256), 0, stream>>>(xb, wt, (float*)d_out);
    } else {
        qkv_gemm<<<dim3((M_DIM / BM) * (N_TOT / BN)), dim3(256), 0, stream>>>(
            x, wq, wk, wv, (float*)d_out);
    }
}